// Round 4
// baseline (2546.817 us; speedup 1.0000x reference)
//
#include <hip/hip_runtime.h>
#include <math.h>

#define N_ROWS 10816   // 64 * 169 rows per timestep
#define T_SEQ 55
#define NPIX 169

__device__ __forceinline__ unsigned short f2bf(float f){
    unsigned u = __float_as_uint(f);
    unsigned r = u + 0x7FFFu + ((u>>16)&1u);
    return (unsigned short)(r>>16);
}
__device__ __forceinline__ float bf2f(unsigned short h){
    return __uint_as_float(((unsigned)h)<<16);
}

// native-exp activations (v_exp_f32 based). NaN-safe at extremes.
__device__ __forceinline__ float fast_sig(float x){
    return 1.0f/(1.0f + __expf(-x));
}
__device__ __forceinline__ float fast_tanh(float x){
    float ax = fabsf(x);
    float e  = __expf(-2.0f*ax);           // (0,1]
    float r  = (1.0f - e)/(1.0f + e);
    return copysignf(r, x);
}

typedef __attribute__((ext_vector_type(8))) short bfrag;
typedef __attribute__((ext_vector_type(4))) float facc;

// ---------------------------------------------------------------------------
// Kernel 1: fused input transpose + 4x (1x1 conv + ReLU) chain. (unchanged)
// ---------------------------------------------------------------------------
__global__ __launch_bounds__(256) void conv1x1_chain(
    const float* __restrict__ x,
    const float* __restrict__ w0, const float* __restrict__ b0,
    const float* __restrict__ w1, const float* __restrict__ b1,
    const float* __restrict__ w2, const float* __restrict__ b2,
    const float* __restrict__ w3, const float* __restrict__ b3,
    float* __restrict__ out)
{
    int n = blockIdx.x*256 + threadIdx.x;
    int l = blockIdx.y;
    if (n >= N_ROWS) return;
    const float* xp = x + ((size_t)n*T_SEQ + l)*24;
    float in24[24];
    #pragma unroll
    for (int i=0;i<6;i++){
        float4 v = *(const float4*)(xp + 4*i);
        in24[4*i]=v.x; in24[4*i+1]=v.y; in24[4*i+2]=v.z; in24[4*i+3]=v.w;
    }
    float a[30], c[30];
    #pragma unroll
    for (int co=0;co<30;co++) a[co]=b0[co];
    #pragma unroll
    for (int ci=0;ci<24;ci++){
        float v = in24[ci];
        #pragma unroll
        for (int co=0;co<30;co++) a[co] = fmaf(v, w0[ci*30+co], a[co]);
    }
    #pragma unroll
    for (int co=0;co<30;co++) a[co] = fmaxf(a[co],0.f);

#define LAYER30(wp, bp) \
    { _Pragma("unroll") for (int co=0;co<30;co++) c[co]=(bp)[co]; \
      _Pragma("unroll") for (int ci=0;ci<30;ci++){ float v=a[ci]; \
        _Pragma("unroll") for (int co=0;co<30;co++) c[co]=fmaf(v,(wp)[ci*30+co],c[co]); } \
      _Pragma("unroll") for (int co=0;co<30;co++) a[co]=fmaxf(c[co],0.f); }

    LAYER30(w1,b1);
    LAYER30(w2,b2);
    LAYER30(w3,b3);
#undef LAYER30

    float* op = out + (size_t)l*30*N_ROWS + n;
    #pragma unroll
    for (int co=0;co<30;co++) op[(size_t)co*N_ROWS] = a[co];
}

// ---------------------------------------------------------------------------
// Kernel 2a: conv weight repack for MFMA, bf16 hi/lo. (unchanged)
// ---------------------------------------------------------------------------
__global__ __launch_bounds__(256) void repack_conv(
    const float* __restrict__ w20, const float* __restrict__ w21,
    const float* __restrict__ w22, const float* __restrict__ w23,
    unsigned short* __restrict__ cwh, unsigned short* __restrict__ cwl)
{
    int i = blockIdx.x*256 + threadIdx.x;
    if (i >= 4*25600) return;
    int layer = i / 25600, r = i - layer*25600;
    int frag = r >> 9, e = r & 511;
    int kt = frag >> 1, ct = frag & 1;
    int lane = e >> 3, j = e & 7;
    int ci = ((lane>>4)<<3) + j;
    int co = ct*16 + (lane & 15);
    const float* w = (layer==0)?w20:(layer==1)?w21:(layer==2)?w22:w23;
    float v = (ci<30 && co<30) ? w[(size_t)(kt*30 + ci)*30 + co] : 0.f;
    unsigned short h = f2bf(v);
    cwh[i] = h; cwl[i] = f2bf(v - bf2f(h));
}

// ---------------------------------------------------------------------------
// Kernel 2b: 5x5 SAME conv + ReLU via split-bf16 MFMA, IN-PLACE. (unchanged)
// ---------------------------------------------------------------------------
__global__ __launch_bounds__(256, 4) void conv5x5_mfma(
    float* __restrict__ buf,
    const unsigned short* __restrict__ cwh, const unsigned short* __restrict__ cwl,
    const float* __restrict__ bias)
{
    __shared__ __align__(16) unsigned short imgh[18*17*32];  // 19584 B
    __shared__ __align__(16) unsigned short imgl[18*17*32];

    int bi = blockIdx.x;
    int l = bi >> 6, b = bi & 63;
    float* ip = buf + (size_t)l*30*N_ROWS + (size_t)b*NPIX;
    const int tid = threadIdx.x;
    const int wave = tid >> 6, lane = tid & 63;
    const int m16 = lane & 15, quad = lane >> 4;

    {
        unsigned* zh = (unsigned*)imgh; unsigned* zl = (unsigned*)imgl;
        for (int i=tid; i<18*17*16; i+=256){ zh[i]=0u; zl[i]=0u; }
    }
    __syncthreads();

    for (int i=tid; i<30*NPIX; i+=256){
        int ci = i / NPIX, p = i - ci*NPIX;
        int py = p/13, px = p - py*13;
        float v = ip[(size_t)ci*N_ROWS + p];
        int L = (py+2)*17 + (px+2);
        int o = L*32 + ((((ci>>3) + L)&3)<<3) + (ci&7);
        unsigned short hh = f2bf(v);
        imgh[o] = hh; imgl[o] = f2bf(v - bf2f(hh));
    }
    __syncthreads();

    float bb[2];
    #pragma unroll
    for (int nt=0; nt<2; nt++){
        int co = nt*16 + m16;
        bb[nt] = (co < 30) ? bias[co] : 0.f;
    }
    facc acc[3][2];
    #pragma unroll
    for (int mi=0; mi<3; mi++)
        #pragma unroll
        for (int nt=0; nt<2; nt++)
            acc[mi][nt] = (facc){bb[nt], bb[nt], bb[nt], bb[nt]};

    int pL[3]; bool mv[3];
    #pragma unroll
    for (int mi=0; mi<3; mi++){
        int Mt = wave + mi*4;
        mv[mi] = (Mt < 11);
        int p = Mt*16 + m16;
        int py = p/13, px = p - py*13;
        pL[mi] = py*17 + px;
    }

    #pragma unroll 1
    for (int kt=0; kt<25; kt++){
        int dy = kt/5, dx = kt - dy*5;
        int Ld = dy*17 + dx;
        bfrag ah[3], al[3];
        #pragma unroll
        for (int mi=0; mi<3; mi++){
            if (mv[mi]){
                int L = pL[mi] + Ld;
                int o = L*32 + (((quad + L)&3)<<3);
                ah[mi] = *(const bfrag*)(imgh + o);
                al[mi] = *(const bfrag*)(imgl + o);
            }
        }
        const unsigned short* whp = cwh + (size_t)(kt*2)*512 + lane*8;
        const unsigned short* wlp = cwl + (size_t)(kt*2)*512 + lane*8;
        bfrag bh0 = *(const bfrag*)(whp);
        bfrag bh1 = *(const bfrag*)(whp + 512);
        bfrag bl0 = *(const bfrag*)(wlp);
        bfrag bl1 = *(const bfrag*)(wlp + 512);
        #pragma unroll
        for (int mi=0; mi<3; mi++){
            if (mv[mi]){
                acc[mi][0] = __builtin_amdgcn_mfma_f32_16x16x32_bf16(ah[mi], bh0, acc[mi][0],0,0,0);
                acc[mi][1] = __builtin_amdgcn_mfma_f32_16x16x32_bf16(ah[mi], bh1, acc[mi][1],0,0,0);
            }
        }
        #pragma unroll
        for (int mi=0; mi<3; mi++){
            if (mv[mi]){
                acc[mi][0] = __builtin_amdgcn_mfma_f32_16x16x32_bf16(al[mi], bh0, acc[mi][0],0,0,0);
                acc[mi][1] = __builtin_amdgcn_mfma_f32_16x16x32_bf16(al[mi], bh1, acc[mi][1],0,0,0);
            }
        }
        #pragma unroll
        for (int mi=0; mi<3; mi++){
            if (mv[mi]){
                acc[mi][0] = __builtin_amdgcn_mfma_f32_16x16x32_bf16(ah[mi], bl0, acc[mi][0],0,0,0);
                acc[mi][1] = __builtin_amdgcn_mfma_f32_16x16x32_bf16(ah[mi], bl1, acc[mi][1],0,0,0);
            }
        }
    }

    #pragma unroll
    for (int mi=0; mi<3; mi++){
        if (mv[mi]){
            int Mt = wave + mi*4;
            #pragma unroll
            for (int nt=0; nt<2; nt++){
                int co = nt*16 + m16;
                if (co < 30){
                    #pragma unroll
                    for (int i2=0; i2<4; i2++){
                        int p = Mt*16 + quad*4 + i2;
                        if (p < NPIX)
                            ip[(size_t)co*N_ROWS + p] = fmaxf(acc[mi][nt][i2], 0.f);
                    }
                }
            }
        }
    }
}

// ---------------------------------------------------------------------------
// Kernel 3: LSTM MFMA weight repack, bf16 hi/lo split. (unchanged)
// ---------------------------------------------------------------------------
__global__ __launch_bounds__(256) void repack_mfma(
    const float* __restrict__ l1w, const float* __restrict__ l1b,
    const float* __restrict__ l2w, const float* __restrict__ l2b,
    unsigned short* __restrict__ bw1h, unsigned short* __restrict__ bw1l,
    unsigned short* __restrict__ bw2h, unsigned short* __restrict__ bw2l,
    float* __restrict__ pbias1, float* __restrict__ pbias2)
{
    const int S1 = 5*32*512;   // 81920
    const int S2 = 7*32*512;   // 114688
    int i = blockIdx.x*256 + threadIdx.x;
    if (i < S1){
        int fr = i >> 9, r = i & 511;
        int kt = fr >> 5, ct = fr & 31;
        int lane = r >> 3, j = r & 7;
        int k = kt*32 + ((lane>>4)<<3) + j;
        int n = lane & 15;
        int cell = ((ct>>2)<<4) + n, g = ct & 3;
        float w = (k<130 && cell<100) ? l1w[(size_t)k*400 + g*100 + cell] : 0.f;
        unsigned short h = f2bf(w);
        bw1h[i] = h; bw1l[i] = f2bf(w - bf2f(h));
    } else if (i < S1 + S2){
        int ii = i - S1;
        int fr = ii >> 9, r = ii & 511;
        int kt = fr >> 5, ct = fr & 31;
        int lane = r >> 3, j = r & 7;
        int k = kt*32 + ((lane>>4)<<3) + j;
        int n = lane & 15;
        int cell = ((ct>>2)<<4) + n, g = ct & 3;
        float w = (k<200 && cell<100) ? l2w[(size_t)k*400 + g*100 + cell] : 0.f;
        unsigned short h = f2bf(w);
        bw2h[ii] = h; bw2l[ii] = f2bf(w - bf2f(h));
    } else if (i < S1+S2+512){
        int col = i - S1 - S2;
        int ct = col >> 4, n = col & 15;
        int cell = ((ct>>2)<<4) + n, g = ct & 3;
        pbias1[col] = (cell<100) ? l1b[g*100+cell] : 0.f;
    } else if (i < S1+S2+1024){
        int col = i - S1 - S2 - 512;
        int ct = col >> 4, n = col & 15;
        int cell = ((ct>>2)<<4) + n, g = ct & 3;
        pbias2[col] = (cell<100) ? l2b[g*100+cell] : 0.f;
    }
}

// ---------------------------------------------------------------------------
// Kernel 4: PERSISTENT 2-layer LSTM + projection, v6 (software-pipelined).
// R3 counters: 33% idle, MfmaUtil 25, VALUBusy 42 -> exposed L2 latency in
// the unroll-1 kt loop (loads at iter top, pass-1 consumes bh immediately;
// compiler can't pipeline across the back-edge). Fix at source, SAME regs
// (WAR-safe: prior MFMAs issue before prefetch write-back):
//   - blv (pass-3 operand) loads at iter top  -> 16 MFMA of cover
//   - bh/alv for kt+1 load after pass 2       -> pass-3 + loop cover
//   - ahv for kt+1 loads after pass 3
//   - cross-phase: EPI1 preloads GEMM2 kt0 bh; EPI2 preloads GEMM1 kt0 bh
// Pass/accumulation order unchanged -> bit-identical numerics vs R3.
// ---------------------------------------------------------------------------
#define NKT1 5
#define NKT2 7
__global__ __launch_bounds__(256, 3) void lstm_mfma5(
    const float* __restrict__ xall,   // [55][30][N]
    const unsigned short* __restrict__ bw1h, const unsigned short* __restrict__ bw1l,
    const unsigned short* __restrict__ bw2h, const unsigned short* __restrict__ bw2l,
    const float* __restrict__ pbias1, const float* __restrict__ pbias2,
    const float* __restrict__ we, const float* __restrict__ be,
    float* __restrict__ out)          // [N][55]
{
    // A matrices as bf16 hi/lo, layout [kt][row(16)][kcol(32)] ushort
    __shared__ __align__(16) unsigned short A1h[NKT1*512];
    __shared__ __align__(16) unsigned short A1l[NKT1*512];
    __shared__ __align__(16) unsigned short A2h[NKT2*512];
    __shared__ __align__(16) unsigned short A2l[NKT2*512];
    __shared__ float pbuf[64];

    const int tid  = threadIdx.x;
    const int wave = tid >> 6, lane = tid & 63;
    const int m16  = lane & 15, quad = lane >> 4;
    const int n0   = blockIdx.x * 16;
    const int cl0  = wave*2;              // my 2 cell-tiles
    const int cell0 = cl0*16 + m16;
    const int cell1 = cell0 + 16;

    for (int i=tid; i<NKT1*512; i+=256){ A1h[i]=0; A1l[i]=0; }
    for (int i=tid; i<NKT2*512; i+=256){ A2h[i]=0; A2l[i]=0; }

    float cs1a[4]={0,0,0,0}, cs1b[4]={0,0,0,0};
    float cs2a[4]={0,0,0,0}, cs2b[4]={0,0,0,0};
    float b1a[4], b1b[4], b2a[4], b2b[4];
    #pragma unroll
    for (int g=0; g<4; g++){
        b1a[g] = pbias1[(cl0*4+g)*16 + m16];
        b1b[g] = pbias1[((cl0+1)*4+g)*16 + m16];
        b2a[g] = pbias2[(cl0*4+g)*16 + m16];
        b2b[g] = pbias2[((cl0+1)*4+g)*16 + m16];
    }
    const float weA = (cell0 < 100) ? we[cell0] : 0.f;
    const float weB = (cell1 < 100) ? we[cell1] : 0.f;
    const float be0 = be[0];

    // weight fragment bases (per kt: advance 32*64*8 = 16384 ushorts)
    const unsigned short* w1h0 = bw1h + ((size_t)(cl0*4)*64 + lane)*8;
    const unsigned short* w1l0 = bw1l + ((size_t)(cl0*4)*64 + lane)*8;
    const unsigned short* w2h0 = bw2h + ((size_t)(cl0*4)*64 + lane)*8;
    const unsigned short* w2l0 = bw2l + ((size_t)(cl0*4)*64 + lane)*8;

    const int sk = tid >> 2, sq = tid & 3;   // staging role (tid<120)

    __syncthreads();   // zero-init visible

    // stage x(0): column sk, rows sq*4..sq*4+3 (all in kt=0, k<30)
    if (tid < 120){
        float4 v = *(const float4*)(xall + (size_t)sk*N_ROWS + n0 + sq*4);
        float vv[4] = {v.x, v.y, v.z, v.w};
        #pragma unroll
        for (int j=0;j<4;j++){
            unsigned short hh = f2bf(vv[j]);
            A1h[(sq*4+j)*32 + sk] = hh;
            A1l[(sq*4+j)*32 + sk] = f2bf(vv[j] - bf2f(hh));
        }
    }
    __syncthreads();

    // pipeline registers (persist across GEMM/EPI phases)
    facc acA[4], acB[4];
    bfrag bh[8], blv[8], ahv, alv;

// preload the 8 bh fragments for the next GEMM's kt=0 (base W0)
#define PRELOADH(W0) \
    { const unsigned short* _wa = (W0); const unsigned short* _wb = (W0) + 2048; \
      _Pragma("unroll") for (int g=0; g<4; g++) bh[g]   = *(const bfrag*)(_wa + (size_t)g*512); \
      _Pragma("unroll") for (int g=0; g<4; g++) bh[4+g] = *(const bfrag*)(_wb + (size_t)g*512); }

// software-pipelined 3-term split GEMM. bh for kt=0 must be preloaded.
#define GEMM(WH0, WL0, NKT, AH, AL, BIA, BIB) \
    { _Pragma("unroll") \
      for (int g=0; g<4; g++){ \
          acA[g]=(facc){(BIA)[g],(BIA)[g],(BIA)[g],(BIA)[g]}; \
          acB[g]=(facc){(BIB)[g],(BIB)[g],(BIB)[g],(BIB)[g]}; } \
      ahv = *(const bfrag*)((AH) + (m16<<5) + (quad<<3)); \
      alv = *(const bfrag*)((AL) + (m16<<5) + (quad<<3)); \
      _Pragma("unroll 1") \
      for (int kt=0; kt<(NKT); kt++){ \
        const unsigned short* wlp  = (WL0) + (size_t)kt*16384; \
        const unsigned short* wlp2 = wlp + 2048; \
        _Pragma("unroll") for (int g=0; g<4; g++) blv[g]   = *(const bfrag*)(wlp  + (size_t)g*512); \
        _Pragma("unroll") for (int g=0; g<4; g++) blv[4+g] = *(const bfrag*)(wlp2 + (size_t)g*512); \
        /* pass 1: ah * bh */ \
        _Pragma("unroll") \
        for (int g=0; g<4; g++){ \
            acA[g]=__builtin_amdgcn_mfma_f32_16x16x32_bf16(ahv,bh[g],  acA[g],0,0,0); \
            acB[g]=__builtin_amdgcn_mfma_f32_16x16x32_bf16(ahv,bh[4+g],acB[g],0,0,0); } \
        /* pass 2: al * bh */ \
        _Pragma("unroll") \
        for (int g=0; g<4; g++){ \
            acA[g]=__builtin_amdgcn_mfma_f32_16x16x32_bf16(alv,bh[g],  acA[g],0,0,0); \
            acB[g]=__builtin_amdgcn_mfma_f32_16x16x32_bf16(alv,bh[4+g],acB[g],0,0,0); } \
        /* prefetch kt+1 bh + alv (WAR-safe: pass1/2 already issued) */ \
        if (kt+1 < (NKT)){ \
            const unsigned short* whn  = (WH0) + (size_t)(kt+1)*16384; \
            const unsigned short* whn2 = whn + 2048; \
            _Pragma("unroll") for (int g=0; g<4; g++) bh[g]   = *(const bfrag*)(whn  + (size_t)g*512); \
            _Pragma("unroll") for (int g=0; g<4; g++) bh[4+g] = *(const bfrag*)(whn2 + (size_t)g*512); \
            alv = *(const bfrag*)((AL) + ((kt+1)<<9) + (m16<<5) + (quad<<3)); \
        } \
        /* pass 3: ah * bl */ \
        _Pragma("unroll") \
        for (int g=0; g<4; g++){ \
            acA[g]=__builtin_amdgcn_mfma_f32_16x16x32_bf16(ahv,blv[g],  acA[g],0,0,0); \
            acB[g]=__builtin_amdgcn_mfma_f32_16x16x32_bf16(ahv,blv[4+g],acB[g],0,0,0); } \
        if (kt+1 < (NKT)) \
            ahv = *(const bfrag*)((AH) + ((kt+1)<<9) + (m16<<5) + (quad<<3)); \
      } }

#define LSTM_CELL(AC, CS, H4) \
    { _Pragma("unroll") \
      for (int i2=0;i2<4;i2++){ \
        float gi = fast_sig((AC)[0][i2]); \
        float gj = fast_tanh((AC)[1][i2]); \
        float gf = fast_sig((AC)[2][i2] + 1.0f); \
        float go = fast_sig((AC)[3][i2]); \
        float cn = gf*(CS)[i2] + gi*gj; \
        (CS)[i2] = cn; \
        (H4)[i2] = go*fast_tanh(cn); } }

    PRELOADH(w1h0);   // GEMM1(t=0) kt=0

    for (int t=0; t<T_SEQ; t++){
        // prefetch x(t+1); latency hidden under GEMM1
        float4 xn;
        if (t+1 < T_SEQ && tid < 120)
            xn = *(const float4*)(xall + ((size_t)(t+1)*30+sk)*N_ROWS + n0 + sq*4);

        GEMM(w1h0, w1l0, NKT1, A1h, A1l, b1a, b1b);        // layer 1
        __syncthreads();                                   // B1

        // EPI1: preload GEMM2 kt0 bh, then h1 -> A1 (k=30+cell), A2 (k=cell)
        {
            PRELOADH(w2h0);
            float hA[4], hB[4];
            LSTM_CELL(acA, cs1a, hA);
            LSTM_CELL(acB, cs1b, hB);
            #pragma unroll
            for (int i2=0;i2<4;i2++){
                int row = quad*4 + i2;
                if (cell0 < 100){
                    unsigned short hh = f2bf(hA[i2]);
                    unsigned short hl = f2bf(hA[i2] - bf2f(hh));
                    int k1 = 30 + cell0;
                    int a1 = ((k1>>5)<<9) + (row<<5) + (k1&31);
                    int a2 = ((cell0>>5)<<9) + (row<<5) + (cell0&31);
                    A1h[a1]=hh; A1l[a1]=hl;
                    A2h[a2]=hh; A2l[a2]=hl;
                }
                if (cell1 < 100){
                    unsigned short hh = f2bf(hB[i2]);
                    unsigned short hl = f2bf(hB[i2] - bf2f(hh));
                    int k1 = 30 + cell1;
                    int a1 = ((k1>>5)<<9) + (row<<5) + (k1&31);
                    int a2 = ((cell1>>5)<<9) + (row<<5) + (cell1&31);
                    A1h[a1]=hh; A1l[a1]=hl;
                    A2h[a2]=hh; A2l[a2]=hl;
                }
            }
            // stage x(t+1) into A1 (GEMM1(t) already read it; next read after B2)
            if (t+1 < T_SEQ && tid < 120){
                float vv[4] = {xn.x, xn.y, xn.z, xn.w};
                #pragma unroll
                for (int j=0;j<4;j++){
                    unsigned short hh = f2bf(vv[j]);
                    A1h[(sq*4+j)*32 + sk] = hh;
                    A1l[(sq*4+j)*32 + sk] = f2bf(vv[j] - bf2f(hh));
                }
            }
        }
        __syncthreads();                                   // B2

        GEMM(w2h0, w2l0, NKT2, A2h, A2l, b2a, b2b);        // layer 2
        __syncthreads();                                   // B3

        // EPI2: preload GEMM1(t+1) kt0 bh; h2 -> A2 (k=100+cell) + projection
        {
            PRELOADH(w1h0);
            float hA[4], hB[4], pp[4];
            LSTM_CELL(acA, cs2a, hA);
            LSTM_CELL(acB, cs2b, hB);
            #pragma unroll
            for (int i2=0;i2<4;i2++){
                int row = quad*4 + i2;
                if (cell0 < 100){
                    unsigned short hh = f2bf(hA[i2]);
                    unsigned short hl = f2bf(hA[i2] - bf2f(hh));
                    int k1 = 100 + cell0;
                    int a1 = ((k1>>5)<<9) + (row<<5) + (k1&31);
                    A2h[a1]=hh; A2l[a1]=hl;
                }
                if (cell1 < 100){
                    unsigned short hh = f2bf(hB[i2]);
                    unsigned short hl = f2bf(hB[i2] - bf2f(hh));
                    int k1 = 100 + cell1;
                    int a1 = ((k1>>5)<<9) + (row<<5) + (k1&31);
                    A2h[a1]=hh; A2l[a1]=hl;
                }
                pp[i2] = hA[i2]*weA + hB[i2]*weB;   // we==0 pads cells>=100
            }
            // reduce over the 16 lanes (m16) of this quad group
            #pragma unroll
            for (int i2=0;i2<4;i2++){
                float p = pp[i2];
                p += __shfl_xor(p, 1);
                p += __shfl_xor(p, 2);
                p += __shfl_xor(p, 4);
                p += __shfl_xor(p, 8);
                pp[i2] = p;
            }
            if (m16 == 0){
                #pragma unroll
                for (int i2=0;i2<4;i2++)
                    pbuf[wave*16 + quad*4 + i2] = pp[i2];
            }
        }
        __syncthreads();                                   // B4

        if (tid < 16){
            float s = be0 + pbuf[tid] + pbuf[16+tid] + pbuf[32+tid] + pbuf[48+tid];
            out[(size_t)(n0+tid)*T_SEQ + t] = s;
        }
    }
#undef GEMM
#undef LSTM_CELL
#undef PRELOADH
}

// ---------------------------------------------------------------------------
extern "C" void kernel_launch(void* const* d_in, const int* in_sizes, int n_in,
                              void* d_out, int out_size, void* d_ws, size_t ws_size,
                              hipStream_t stream)
{
    const float* x    = (const float*)d_in[0];
    const float* w10  = (const float*)d_in[1];  const float* b10 = (const float*)d_in[2];
    const float* w11  = (const float*)d_in[3];  const float* b11 = (const float*)d_in[4];
    const float* w12  = (const float*)d_in[5];  const float* b12 = (const float*)d_in[6];
    const float* w13  = (const float*)d_in[7];  const float* b13 = (const float*)d_in[8];
    const float* w20  = (const float*)d_in[9];  const float* b20 = (const float*)d_in[10];
    const float* w21  = (const float*)d_in[11]; const float* b21 = (const float*)d_in[12];
    const float* w22  = (const float*)d_in[13]; const float* b22 = (const float*)d_in[14];
    const float* w23  = (const float*)d_in[15]; const float* b23 = (const float*)d_in[16];
    const float* l1w  = (const float*)d_in[17]; const float* l1b = (const float*)d_in[18];
    const float* l2w  = (const float*)d_in[19]; const float* l2b = (const float*)d_in[20];
    const float* we   = (const float*)d_in[21]; const float* be  = (const float*)d_in[22];
    float* out = (float*)d_out;

    // workspace: conv slab 71.4 MB + packed bf16 weights ~0.8 MB + biases.
    // Conv packs (409.6 KB) OVERLAY the lstm pack region and are consumed
    // before repack_mfma overwrites it (stream-serialized) -> no extra ws.
    const size_t NF = (size_t)30*N_ROWS;
    float* buf0 = (float*)d_ws;                       // [55][30][N] floats
    unsigned short* bw1h = (unsigned short*)(buf0 + (size_t)T_SEQ*NF);
    unsigned short* bw1l = bw1h + 5*32*512;           // 81920 each
    unsigned short* bw2h = bw1l + 5*32*512;
    unsigned short* bw2l = bw2h + 7*32*512;           // 114688 each
    float* pbias1 = (float*)(bw2l + 7*32*512);
    float* pbias2 = pbias1 + 512;

    unsigned short* cwh = bw1h;                       // 4*25600 ushorts
    unsigned short* cwl = cwh + 4*25600;              // 4*25600 ushorts

    repack_conv<<<(4*25600+255)/256, 256, 0, stream>>>(w20, w21, w22, w23, cwh, cwl);

    dim3 g1((N_ROWS+255)/256, T_SEQ);
    conv1x1_chain<<<g1, 256, 0, stream>>>(x, w10,b10, w11,b11, w12,b12, w13,b13, buf0);

    conv5x5_mfma<<<T_SEQ*64, 256, 0, stream>>>(buf0, cwh,         cwl,         b20);
    conv5x5_mfma<<<T_SEQ*64, 256, 0, stream>>>(buf0, cwh+25600,   cwl+25600,   b21);
    conv5x5_mfma<<<T_SEQ*64, 256, 0, stream>>>(buf0, cwh+2*25600, cwl+2*25600, b22);
    conv5x5_mfma<<<T_SEQ*64, 256, 0, stream>>>(buf0, cwh+3*25600, cwl+3*25600, b23);

    const int REPACK_N = 5*32*512 + 7*32*512 + 1024;
    repack_mfma<<<(REPACK_N+255)/256, 256, 0, stream>>>(
        l1w, l1b, l2w, l2b, bw1h, bw1l, bw2h, bw2l, pbias1, pbias2);

    lstm_mfma5<<<N_ROWS/16, 256, 0, stream>>>(buf0, bw1h, bw1l, bw2h, bw2l,
                                              pbias1, pbias2, we, be, out);
}

// Round 5
// 1631.619 us; speedup vs baseline: 1.5609x; 1.5609x over previous
//
#include <hip/hip_runtime.h>
#include <math.h>

#define N_ROWS 10816   // 64 * 169 rows per timestep
#define T_SEQ 55
#define NPIX 169

__device__ __forceinline__ unsigned short f2bf(float f){
    unsigned u = __float_as_uint(f);
    unsigned r = u + 0x7FFFu + ((u>>16)&1u);
    return (unsigned short)(r>>16);
}
__device__ __forceinline__ float bf2f(unsigned short h){
    return __uint_as_float(((unsigned)h)<<16);
}

// native-exp activations (v_exp_f32 based). NaN-safe at extremes.
__device__ __forceinline__ float fast_sig(float x){
    return 1.0f/(1.0f + __expf(-x));
}
__device__ __forceinline__ float fast_tanh(float x){
    float ax = fabsf(x);
    float e  = __expf(-2.0f*ax);           // (0,1]
    float r  = (1.0f - e)/(1.0f + e);
    return copysignf(r, x);
}

typedef __attribute__((ext_vector_type(8))) short bfrag;
typedef __attribute__((ext_vector_type(4))) float facc;

// ---------------------------------------------------------------------------
// Kernel 1: fused input transpose + 4x (1x1 conv + ReLU) chain. (unchanged)
// ---------------------------------------------------------------------------
__global__ __launch_bounds__(256) void conv1x1_chain(
    const float* __restrict__ x,
    const float* __restrict__ w0, const float* __restrict__ b0,
    const float* __restrict__ w1, const float* __restrict__ b1,
    const float* __restrict__ w2, const float* __restrict__ b2,
    const float* __restrict__ w3, const float* __restrict__ b3,
    float* __restrict__ out)
{
    int n = blockIdx.x*256 + threadIdx.x;
    int l = blockIdx.y;
    if (n >= N_ROWS) return;
    const float* xp = x + ((size_t)n*T_SEQ + l)*24;
    float in24[24];
    #pragma unroll
    for (int i=0;i<6;i++){
        float4 v = *(const float4*)(xp + 4*i);
        in24[4*i]=v.x; in24[4*i+1]=v.y; in24[4*i+2]=v.z; in24[4*i+3]=v.w;
    }
    float a[30], c[30];
    #pragma unroll
    for (int co=0;co<30;co++) a[co]=b0[co];
    #pragma unroll
    for (int ci=0;ci<24;ci++){
        float v = in24[ci];
        #pragma unroll
        for (int co=0;co<30;co++) a[co] = fmaf(v, w0[ci*30+co], a[co]);
    }
    #pragma unroll
    for (int co=0;co<30;co++) a[co] = fmaxf(a[co],0.f);

#define LAYER30(wp, bp) \
    { _Pragma("unroll") for (int co=0;co<30;co++) c[co]=(bp)[co]; \
      _Pragma("unroll") for (int ci=0;ci<30;ci++){ float v=a[ci]; \
        _Pragma("unroll") for (int co=0;co<30;co++) c[co]=fmaf(v,(wp)[ci*30+co],c[co]); } \
      _Pragma("unroll") for (int co=0;co<30;co++) a[co]=fmaxf(c[co],0.f); }

    LAYER30(w1,b1);
    LAYER30(w2,b2);
    LAYER30(w3,b3);
#undef LAYER30

    float* op = out + (size_t)l*30*N_ROWS + n;
    #pragma unroll
    for (int co=0;co<30;co++) op[(size_t)co*N_ROWS] = a[co];
}

// ---------------------------------------------------------------------------
// Kernel 2a: conv weight repack for MFMA, bf16 hi/lo. (unchanged)
// ---------------------------------------------------------------------------
__global__ __launch_bounds__(256) void repack_conv(
    const float* __restrict__ w20, const float* __restrict__ w21,
    const float* __restrict__ w22, const float* __restrict__ w23,
    unsigned short* __restrict__ cwh, unsigned short* __restrict__ cwl)
{
    int i = blockIdx.x*256 + threadIdx.x;
    if (i >= 4*25600) return;
    int layer = i / 25600, r = i - layer*25600;
    int frag = r >> 9, e = r & 511;
    int kt = frag >> 1, ct = frag & 1;
    int lane = e >> 3, j = e & 7;
    int ci = ((lane>>4)<<3) + j;
    int co = ct*16 + (lane & 15);
    const float* w = (layer==0)?w20:(layer==1)?w21:(layer==2)?w22:w23;
    float v = (ci<30 && co<30) ? w[(size_t)(kt*30 + ci)*30 + co] : 0.f;
    unsigned short h = f2bf(v);
    cwh[i] = h; cwl[i] = f2bf(v - bf2f(h));
}

// ---------------------------------------------------------------------------
// Kernel 2b: FUSED 4-layer 5x5 SAME conv + ReLU via split-bf16 MFMA.
// R4 insight: image is 13x13 -> whole image + halo lives in block LDS, so
// all 4 layers run in one kernel with __syncthreads between layers.
// Eliminates 3x (71MB slab write + read), 3x image stage/f2bf, 3 launches
// (~70% of each separate dispatch was staging overhead; MFMA floor is
// ~11.5 us/layer). Per-layer math identical to R3 -> bit-identical output.
// Inter-layer: GEMM reads img; sync; writeback ReLU into img (co 0..29,
// interior only -- ci 30/31 and halo stay zero from init); sync at loop top.
// ---------------------------------------------------------------------------
__global__ __launch_bounds__(256, 4) void conv5x5_mfma4(
    float* __restrict__ buf,
    const unsigned short* __restrict__ cwh, const unsigned short* __restrict__ cwl,
    const float* __restrict__ bias0, const float* __restrict__ bias1,
    const float* __restrict__ bias2, const float* __restrict__ bias3)
{
    __shared__ __align__(16) unsigned short imgh[18*17*32];  // 19584 B
    __shared__ __align__(16) unsigned short imgl[18*17*32];

    int bi = blockIdx.x;
    int l = bi >> 6, b = bi & 63;
    float* ip = buf + (size_t)l*30*N_ROWS + (size_t)b*NPIX;
    const int tid = threadIdx.x;
    const int wave = tid >> 6, lane = tid & 63;
    const int m16 = lane & 15, quad = lane >> 4;

    // zero-init LDS (pad borders + ci 30/31 stay zero forever)
    {
        unsigned* zh = (unsigned*)imgh; unsigned* zl = (unsigned*)imgl;
        for (int i=tid; i<18*17*16; i+=256){ zh[i]=0u; zl[i]=0u; }
    }
    __syncthreads();

    // stage image ONCE: [ci][p] global -> [row][col][ci] LDS bf16 h/l
    for (int i=tid; i<30*NPIX; i+=256){
        int ci = i / NPIX, p = i - ci*NPIX;
        int py = p/13, px = p - py*13;
        float v = ip[(size_t)ci*N_ROWS + p];
        int L = (py+2)*17 + (px+2);
        int o = L*32 + ((((ci>>3) + L)&3)<<3) + (ci&7);
        unsigned short hh = f2bf(v);
        imgh[o] = hh; imgl[o] = f2bf(v - bf2f(hh));
    }

    // per-M-tile pixel bases (layer/kt-invariant)
    int pL[3]; bool mv[3];
    #pragma unroll
    for (int mi=0; mi<3; mi++){
        int Mt = wave + mi*4;
        mv[mi] = (Mt < 11);
        int p = Mt*16 + m16;
        int py = p/13, px = p - py*13;
        pL[mi] = py*17 + px;
    }

    #pragma unroll 1
    for (int layer=0; layer<4; layer++){
        const float* bias = (layer==0)?bias0:(layer==1)?bias1:(layer==2)?bias2:bias3;
        const unsigned short* wh = cwh + (size_t)layer*25600;
        const unsigned short* wl = cwl + (size_t)layer*25600;

        __syncthreads();   // staging (layer 0) / writeback (layers 1-3) visible

        float bb[2];
        #pragma unroll
        for (int nt=0; nt<2; nt++){
            int co = nt*16 + m16;
            bb[nt] = (co < 30) ? bias[co] : 0.f;
        }
        facc acc[3][2];
        #pragma unroll
        for (int mi=0; mi<3; mi++)
            #pragma unroll
            for (int nt=0; nt<2; nt++)
                acc[mi][nt] = (facc){bb[nt], bb[nt], bb[nt], bb[nt]};

        #pragma unroll 1
        for (int kt=0; kt<25; kt++){
            int dy = kt/5, dx = kt - dy*5;
            int Ld = dy*17 + dx;
            bfrag ah[3], al[3];
            #pragma unroll
            for (int mi=0; mi<3; mi++){
                if (mv[mi]){
                    int L = pL[mi] + Ld;
                    int o = L*32 + (((quad + L)&3)<<3);
                    ah[mi] = *(const bfrag*)(imgh + o);
                    al[mi] = *(const bfrag*)(imgl + o);
                }
            }
            const unsigned short* whp = wh + (size_t)(kt*2)*512 + lane*8;
            const unsigned short* wlp = wl + (size_t)(kt*2)*512 + lane*8;
            bfrag bh0 = *(const bfrag*)(whp);
            bfrag bh1 = *(const bfrag*)(whp + 512);
            bfrag bl0 = *(const bfrag*)(wlp);
            bfrag bl1 = *(const bfrag*)(wlp + 512);
            #pragma unroll
            for (int mi=0; mi<3; mi++){
                if (mv[mi]){
                    acc[mi][0] = __builtin_amdgcn_mfma_f32_16x16x32_bf16(ah[mi], bh0, acc[mi][0],0,0,0);
                    acc[mi][1] = __builtin_amdgcn_mfma_f32_16x16x32_bf16(ah[mi], bh1, acc[mi][1],0,0,0);
                }
            }
            #pragma unroll
            for (int mi=0; mi<3; mi++){
                if (mv[mi]){
                    acc[mi][0] = __builtin_amdgcn_mfma_f32_16x16x32_bf16(al[mi], bh0, acc[mi][0],0,0,0);
                    acc[mi][1] = __builtin_amdgcn_mfma_f32_16x16x32_bf16(al[mi], bh1, acc[mi][1],0,0,0);
                }
            }
            #pragma unroll
            for (int mi=0; mi<3; mi++){
                if (mv[mi]){
                    acc[mi][0] = __builtin_amdgcn_mfma_f32_16x16x32_bf16(ah[mi], bl0, acc[mi][0],0,0,0);
                    acc[mi][1] = __builtin_amdgcn_mfma_f32_16x16x32_bf16(ah[mi], bl1, acc[mi][1],0,0,0);
                }
            }
        }

        __syncthreads();   // all img reads of this layer done before overwrite

        if (layer < 3){
            // writeback ReLU(acc) into img (same split + swizzle as staging)
            #pragma unroll
            for (int mi=0; mi<3; mi++){
                if (mv[mi]){
                    int Mt = wave + mi*4;
                    #pragma unroll
                    for (int nt=0; nt<2; nt++){
                        int co = nt*16 + m16;
                        if (co < 30){
                            #pragma unroll
                            for (int i2=0; i2<4; i2++){
                                int p = Mt*16 + quad*4 + i2;
                                if (p < NPIX){
                                    float v = fmaxf(acc[mi][nt][i2], 0.f);
                                    int py = p/13, px = p - py*13;
                                    int L = (py+2)*17 + (px+2);
                                    int o = L*32 + ((((co>>3) + L)&3)<<3) + (co&7);
                                    unsigned short hh = f2bf(v);
                                    imgh[o] = hh; imgl[o] = f2bf(v - bf2f(hh));
                                }
                            }
                        }
                    }
                }
            }
        } else {
            // final layer: store to global
            #pragma unroll
            for (int mi=0; mi<3; mi++){
                if (mv[mi]){
                    int Mt = wave + mi*4;
                    #pragma unroll
                    for (int nt=0; nt<2; nt++){
                        int co = nt*16 + m16;
                        if (co < 30){
                            #pragma unroll
                            for (int i2=0; i2<4; i2++){
                                int p = Mt*16 + quad*4 + i2;
                                if (p < NPIX)
                                    ip[(size_t)co*N_ROWS + p] = fmaxf(acc[mi][nt][i2], 0.f);
                            }
                        }
                    }
                }
            }
        }
    }
}

// ---------------------------------------------------------------------------
// Kernel 3: LSTM MFMA weight repack, bf16 hi/lo split. (unchanged)
// ---------------------------------------------------------------------------
__global__ __launch_bounds__(256) void repack_mfma(
    const float* __restrict__ l1w, const float* __restrict__ l1b,
    const float* __restrict__ l2w, const float* __restrict__ l2b,
    unsigned short* __restrict__ bw1h, unsigned short* __restrict__ bw1l,
    unsigned short* __restrict__ bw2h, unsigned short* __restrict__ bw2l,
    float* __restrict__ pbias1, float* __restrict__ pbias2)
{
    const int S1 = 5*32*512;   // 81920
    const int S2 = 7*32*512;   // 114688
    int i = blockIdx.x*256 + threadIdx.x;
    if (i < S1){
        int fr = i >> 9, r = i & 511;
        int kt = fr >> 5, ct = fr & 31;
        int lane = r >> 3, j = r & 7;
        int k = kt*32 + ((lane>>4)<<3) + j;
        int n = lane & 15;
        int cell = ((ct>>2)<<4) + n, g = ct & 3;
        float w = (k<130 && cell<100) ? l1w[(size_t)k*400 + g*100 + cell] : 0.f;
        unsigned short h = f2bf(w);
        bw1h[i] = h; bw1l[i] = f2bf(w - bf2f(h));
    } else if (i < S1 + S2){
        int ii = i - S1;
        int fr = ii >> 9, r = ii & 511;
        int kt = fr >> 5, ct = fr & 31;
        int lane = r >> 3, j = r & 7;
        int k = kt*32 + ((lane>>4)<<3) + j;
        int n = lane & 15;
        int cell = ((ct>>2)<<4) + n, g = ct & 3;
        float w = (k<200 && cell<100) ? l2w[(size_t)k*400 + g*100 + cell] : 0.f;
        unsigned short h = f2bf(w);
        bw2h[ii] = h; bw2l[ii] = f2bf(w - bf2f(h));
    } else if (i < S1+S2+512){
        int col = i - S1 - S2;
        int ct = col >> 4, n = col & 15;
        int cell = ((ct>>2)<<4) + n, g = ct & 3;
        pbias1[col] = (cell<100) ? l1b[g*100+cell] : 0.f;
    } else if (i < S1+S2+1024){
        int col = i - S1 - S2 - 512;
        int ct = col >> 4, n = col & 15;
        int cell = ((ct>>2)<<4) + n, g = ct & 3;
        pbias2[col] = (cell<100) ? l2b[g*100+cell] : 0.f;
    }
}

// ---------------------------------------------------------------------------
// Kernel 4: PERSISTENT 2-layer LSTM + projection. REVERTED to R3's proven
// lstm_mfma3 (1266 us). R4's explicit cross-phase register pipeline spilled
// to scratch (FETCH 73MB -> 2GB) at the launch_bounds(256,3) budget --
// hand-pinning fragments across barriers defeats hipcc's scheduler.
// ---------------------------------------------------------------------------
#define NKT1 5
#define NKT2 7
__global__ __launch_bounds__(256, 3) void lstm_mfma3(
    const float* __restrict__ xall,   // [55][30][N]
    const unsigned short* __restrict__ bw1h, const unsigned short* __restrict__ bw1l,
    const unsigned short* __restrict__ bw2h, const unsigned short* __restrict__ bw2l,
    const float* __restrict__ pbias1, const float* __restrict__ pbias2,
    const float* __restrict__ we, const float* __restrict__ be,
    float* __restrict__ out)          // [N][55]
{
    // A matrices as bf16 hi/lo, layout [kt][row(16)][kcol(32)] ushort
    __shared__ __align__(16) unsigned short A1h[NKT1*512];
    __shared__ __align__(16) unsigned short A1l[NKT1*512];
    __shared__ __align__(16) unsigned short A2h[NKT2*512];
    __shared__ __align__(16) unsigned short A2l[NKT2*512];
    __shared__ float pbuf[64];

    const int tid  = threadIdx.x;
    const int wave = tid >> 6, lane = tid & 63;
    const int m16  = lane & 15, quad = lane >> 4;
    const int n0   = blockIdx.x * 16;
    const int cl0  = wave*2;              // my 2 cell-tiles
    const int cell0 = cl0*16 + m16;
    const int cell1 = cell0 + 16;

    for (int i=tid; i<NKT1*512; i+=256){ A1h[i]=0; A1l[i]=0; }
    for (int i=tid; i<NKT2*512; i+=256){ A2h[i]=0; A2l[i]=0; }

    float cs1a[4]={0,0,0,0}, cs1b[4]={0,0,0,0};
    float cs2a[4]={0,0,0,0}, cs2b[4]={0,0,0,0};
    float b1a[4], b1b[4], b2a[4], b2b[4];
    #pragma unroll
    for (int g=0; g<4; g++){
        b1a[g] = pbias1[(cl0*4+g)*16 + m16];
        b1b[g] = pbias1[((cl0+1)*4+g)*16 + m16];
        b2a[g] = pbias2[(cl0*4+g)*16 + m16];
        b2b[g] = pbias2[((cl0+1)*4+g)*16 + m16];
    }
    const float weA = (cell0 < 100) ? we[cell0] : 0.f;
    const float weB = (cell1 < 100) ? we[cell1] : 0.f;
    const float be0 = be[0];

    // weight fragment bases (per kt: advance 32*64*8 = 16384 ushorts)
    const unsigned short* w1h0 = bw1h + ((size_t)(cl0*4)*64 + lane)*8;
    const unsigned short* w1l0 = bw1l + ((size_t)(cl0*4)*64 + lane)*8;
    const unsigned short* w2h0 = bw2h + ((size_t)(cl0*4)*64 + lane)*8;
    const unsigned short* w2l0 = bw2l + ((size_t)(cl0*4)*64 + lane)*8;

    const int sk = tid >> 2, sq = tid & 3;   // staging role (tid<120)

    __syncthreads();   // zero-init visible

    // stage x(0): column sk, rows sq*4..sq*4+3 (all in kt=0, k<30)
    if (tid < 120){
        float4 v = *(const float4*)(xall + (size_t)sk*N_ROWS + n0 + sq*4);
        float vv[4] = {v.x, v.y, v.z, v.w};
        #pragma unroll
        for (int j=0;j<4;j++){
            unsigned short hh = f2bf(vv[j]);
            A1h[(sq*4+j)*32 + sk] = hh;
            A1l[(sq*4+j)*32 + sk] = f2bf(vv[j] - bf2f(hh));
        }
    }
    __syncthreads();

    facc acA[4], acB[4];

// 3-term split GEMM, pass-interleaved. kt loop NOT unrolled (spill control).
#define GEMM(WH0, WL0, NKT, AH, AL, BIA, BIB) \
    { _Pragma("unroll") \
      for (int g=0; g<4; g++){ \
          acA[g]=(facc){(BIA)[g],(BIA)[g],(BIA)[g],(BIA)[g]}; \
          acB[g]=(facc){(BIB)[g],(BIB)[g],(BIB)[g],(BIB)[g]}; } \
      _Pragma("unroll 1") \
      for (int kt=0; kt<(NKT); kt++){ \
        bfrag ah = *(const bfrag*)((AH) + (kt<<9) + (m16<<5) + (quad<<3)); \
        bfrag al = *(const bfrag*)((AL) + (kt<<9) + (m16<<5) + (quad<<3)); \
        const unsigned short* whp = (WH0) + (size_t)kt*16384; \
        const unsigned short* wlp = (WL0) + (size_t)kt*16384; \
        bfrag bh[8], bl[8]; \
        _Pragma("unroll") \
        for (int g=0; g<8; g++){ \
            bh[g] = *(const bfrag*)(whp + (size_t)g*512); \
            bl[g] = *(const bfrag*)(wlp + (size_t)g*512); } \
        _Pragma("unroll") \
        for (int g=0; g<4; g++){ \
            acA[g]=__builtin_amdgcn_mfma_f32_16x16x32_bf16(ah,bh[g],  acA[g],0,0,0); \
            acB[g]=__builtin_amdgcn_mfma_f32_16x16x32_bf16(ah,bh[4+g],acB[g],0,0,0); } \
        _Pragma("unroll") \
        for (int g=0; g<4; g++){ \
            acA[g]=__builtin_amdgcn_mfma_f32_16x16x32_bf16(al,bh[g],  acA[g],0,0,0); \
            acB[g]=__builtin_amdgcn_mfma_f32_16x16x32_bf16(al,bh[4+g],acB[g],0,0,0); } \
        _Pragma("unroll") \
        for (int g=0; g<4; g++){ \
            acA[g]=__builtin_amdgcn_mfma_f32_16x16x32_bf16(ah,bl[g],  acA[g],0,0,0); \
            acB[g]=__builtin_amdgcn_mfma_f32_16x16x32_bf16(ah,bl[4+g],acB[g],0,0,0); } \
      } }

#define LSTM_CELL(AC, CS, H4) \
    { _Pragma("unroll") \
      for (int i2=0;i2<4;i2++){ \
        float gi = fast_sig((AC)[0][i2]); \
        float gj = fast_tanh((AC)[1][i2]); \
        float gf = fast_sig((AC)[2][i2] + 1.0f); \
        float go = fast_sig((AC)[3][i2]); \
        float cn = gf*(CS)[i2] + gi*gj; \
        (CS)[i2] = cn; \
        (H4)[i2] = go*fast_tanh(cn); } }

    for (int t=0; t<T_SEQ; t++){
        // prefetch x(t+1); latency hidden under GEMM1
        float4 xn;
        if (t+1 < T_SEQ && tid < 120)
            xn = *(const float4*)(xall + ((size_t)(t+1)*30+sk)*N_ROWS + n0 + sq*4);

        GEMM(w1h0, w1l0, NKT1, A1h, A1l, b1a, b1b);        // layer 1
        __syncthreads();                                   // B1

        // EPI1: h1 -> A1 (k=30+cell) and A2 (k=cell), split once
        {
            float hA[4], hB[4];
            LSTM_CELL(acA, cs1a, hA);
            LSTM_CELL(acB, cs1b, hB);
            #pragma unroll
            for (int i2=0;i2<4;i2++){
                int row = quad*4 + i2;
                if (cell0 < 100){
                    unsigned short hh = f2bf(hA[i2]);
                    unsigned short hl = f2bf(hA[i2] - bf2f(hh));
                    int k1 = 30 + cell0;
                    int a1 = ((k1>>5)<<9) + (row<<5) + (k1&31);
                    int a2 = ((cell0>>5)<<9) + (row<<5) + (cell0&31);
                    A1h[a1]=hh; A1l[a1]=hl;
                    A2h[a2]=hh; A2l[a2]=hl;
                }
                if (cell1 < 100){
                    unsigned short hh = f2bf(hB[i2]);
                    unsigned short hl = f2bf(hB[i2] - bf2f(hh));
                    int k1 = 30 + cell1;
                    int a1 = ((k1>>5)<<9) + (row<<5) + (k1&31);
                    int a2 = ((cell1>>5)<<9) + (row<<5) + (cell1&31);
                    A1h[a1]=hh; A1l[a1]=hl;
                    A2h[a2]=hh; A2l[a2]=hl;
                }
            }
            // stage x(t+1) into A1 (GEMM1(t) already read it; next read after B2)
            if (t+1 < T_SEQ && tid < 120){
                float vv[4] = {xn.x, xn.y, xn.z, xn.w};
                #pragma unroll
                for (int j=0;j<4;j++){
                    unsigned short hh = f2bf(vv[j]);
                    A1h[(sq*4+j)*32 + sk] = hh;
                    A1l[(sq*4+j)*32 + sk] = f2bf(vv[j] - bf2f(hh));
                }
            }
        }
        __syncthreads();                                   // B2

        GEMM(w2h0, w2l0, NKT2, A2h, A2l, b2a, b2b);        // layer 2
        __syncthreads();                                   // B3

        // EPI2: h2 -> A2 (k=100+cell) + in-register projection partial
        {
            float hA[4], hB[4], pp[4];
            LSTM_CELL(acA, cs2a, hA);
            LSTM_CELL(acB, cs2b, hB);
            #pragma unroll
            for (int i2=0;i2<4;i2++){
                int row = quad*4 + i2;
                if (cell0 < 100){
                    unsigned short hh = f2bf(hA[i2]);
                    unsigned short hl = f2bf(hA[i2] - bf2f(hh));
                    int k1 = 100 + cell0;
                    int a1 = ((k1>>5)<<9) + (row<<5) + (k1&31);
                    A2h[a1]=hh; A2l[a1]=hl;
                }
                if (cell1 < 100){
                    unsigned short hh = f2bf(hB[i2]);
                    unsigned short hl = f2bf(hB[i2] - bf2f(hh));
                    int k1 = 100 + cell1;
                    int a1 = ((k1>>5)<<9) + (row<<5) + (k1&31);
                    A2h[a1]=hh; A2l[a1]=hl;
                }
                pp[i2] = hA[i2]*weA + hB[i2]*weB;   // we==0 pads cells>=100
            }
            // reduce over the 16 lanes (m16) of this quad group
            #pragma unroll
            for (int i2=0;i2<4;i2++){
                float p = pp[i2];
                p += __shfl_xor(p, 1);
                p += __shfl_xor(p, 2);
                p += __shfl_xor(p, 4);
                p += __shfl_xor(p, 8);
                pp[i2] = p;
            }
            if (m16 == 0){
                #pragma unroll
                for (int i2=0;i2<4;i2++)
                    pbuf[wave*16 + quad*4 + i2] = pp[i2];
            }
        }
        __syncthreads();                                   // B4

        if (tid < 16){
            float s = be0 + pbuf[tid] + pbuf[16+tid] + pbuf[32+tid] + pbuf[48+tid];
            out[(size_t)(n0+tid)*T_SEQ + t] = s;
        }
    }
#undef GEMM
#undef LSTM_CELL
}

// ---------------------------------------------------------------------------
extern "C" void kernel_launch(void* const* d_in, const int* in_sizes, int n_in,
                              void* d_out, int out_size, void* d_ws, size_t ws_size,
                              hipStream_t stream)
{
    const float* x    = (const float*)d_in[0];
    const float* w10  = (const float*)d_in[1];  const float* b10 = (const float*)d_in[2];
    const float* w11  = (const float*)d_in[3];  const float* b11 = (const float*)d_in[4];
    const float* w12  = (const float*)d_in[5];  const float* b12 = (const float*)d_in[6];
    const float* w13  = (const float*)d_in[7];  const float* b13 = (const float*)d_in[8];
    const float* w20  = (const float*)d_in[9];  const float* b20 = (const float*)d_in[10];
    const float* w21  = (const float*)d_in[11]; const float* b21 = (const float*)d_in[12];
    const float* w22  = (const float*)d_in[13]; const float* b22 = (const float*)d_in[14];
    const float* w23  = (const float*)d_in[15]; const float* b23 = (const float*)d_in[16];
    const float* l1w  = (const float*)d_in[17]; const float* l1b = (const float*)d_in[18];
    const float* l2w  = (const float*)d_in[19]; const float* l2b = (const float*)d_in[20];
    const float* we   = (const float*)d_in[21]; const float* be  = (const float*)d_in[22];
    float* out = (float*)d_out;

    // workspace: conv slab 71.4 MB + packed bf16 weights ~0.8 MB + biases.
    // Conv packs (409.6 KB) OVERLAY the lstm pack region and are consumed
    // before repack_mfma overwrites it (stream-serialized) -> no extra ws.
    const size_t NF = (size_t)30*N_ROWS;
    float* buf0 = (float*)d_ws;                       // [55][30][N] floats
    unsigned short* bw1h = (unsigned short*)(buf0 + (size_t)T_SEQ*NF);
    unsigned short* bw1l = bw1h + 5*32*512;           // 81920 each
    unsigned short* bw2h = bw1l + 5*32*512;
    unsigned short* bw2l = bw2h + 7*32*512;           // 114688 each
    float* pbias1 = (float*)(bw2l + 7*32*512);
    float* pbias2 = pbias1 + 512;

    unsigned short* cwh = bw1h;                       // 4*25600 ushorts
    unsigned short* cwl = cwh + 4*25600;              // 4*25600 ushorts

    repack_conv<<<(4*25600+255)/256, 256, 0, stream>>>(w20, w21, w22, w23, cwh, cwl);

    dim3 g1((N_ROWS+255)/256, T_SEQ);
    conv1x1_chain<<<g1, 256, 0, stream>>>(x, w10,b10, w11,b11, w12,b12, w13,b13, buf0);

    conv5x5_mfma4<<<T_SEQ*64, 256, 0, stream>>>(buf0, cwh, cwl, b20, b21, b22, b23);

    const int REPACK_N = 5*32*512 + 7*32*512 + 1024;
    repack_mfma<<<(REPACK_N+255)/256, 256, 0, stream>>>(
        l1w, l1b, l2w, l2b, bw1h, bw1l, bw2h, bw2l, pbias1, pbias2);

    lstm_mfma3<<<N_ROWS/16, 256, 0, stream>>>(buf0, bw1h, bw1l, bw2h, bw2l,
                                              pbias1, pbias2, we, be, out);
}

// Round 6
// 1618.879 us; speedup vs baseline: 1.5732x; 1.0079x over previous
//
#include <hip/hip_runtime.h>
#include <math.h>

#define N_ROWS 10816   // 64 * 169 rows per timestep
#define T_SEQ 55
#define NPIX 169

__device__ __forceinline__ unsigned short f2bf(float f){
    unsigned u = __float_as_uint(f);
    unsigned r = u + 0x7FFFu + ((u>>16)&1u);
    return (unsigned short)(r>>16);
}
__device__ __forceinline__ float bf2f(unsigned short h){
    return __uint_as_float(((unsigned)h)<<16);
}

// native-exp activations (v_exp_f32 based). NaN-safe at extremes.
__device__ __forceinline__ float fast_sig(float x){
    return 1.0f/(1.0f + __expf(-x));
}
__device__ __forceinline__ float fast_tanh(float x){
    float ax = fabsf(x);
    float e  = __expf(-2.0f*ax);           // (0,1]
    float r  = (1.0f - e)/(1.0f + e);
    return copysignf(r, x);
}

typedef __attribute__((ext_vector_type(8))) short bfrag;
typedef __attribute__((ext_vector_type(4))) float facc;

// ---------------------------------------------------------------------------
// Kernel 1: fused input transpose + 4x (1x1 conv + ReLU) chain. (unchanged)
// ---------------------------------------------------------------------------
__global__ __launch_bounds__(256) void conv1x1_chain(
    const float* __restrict__ x,
    const float* __restrict__ w0, const float* __restrict__ b0,
    const float* __restrict__ w1, const float* __restrict__ b1,
    const float* __restrict__ w2, const float* __restrict__ b2,
    const float* __restrict__ w3, const float* __restrict__ b3,
    float* __restrict__ out)
{
    int n = blockIdx.x*256 + threadIdx.x;
    int l = blockIdx.y;
    if (n >= N_ROWS) return;
    const float* xp = x + ((size_t)n*T_SEQ + l)*24;
    float in24[24];
    #pragma unroll
    for (int i=0;i<6;i++){
        float4 v = *(const float4*)(xp + 4*i);
        in24[4*i]=v.x; in24[4*i+1]=v.y; in24[4*i+2]=v.z; in24[4*i+3]=v.w;
    }
    float a[30], c[30];
    #pragma unroll
    for (int co=0;co<30;co++) a[co]=b0[co];
    #pragma unroll
    for (int ci=0;ci<24;ci++){
        float v = in24[ci];
        #pragma unroll
        for (int co=0;co<30;co++) a[co] = fmaf(v, w0[ci*30+co], a[co]);
    }
    #pragma unroll
    for (int co=0;co<30;co++) a[co] = fmaxf(a[co],0.f);

#define LAYER30(wp, bp) \
    { _Pragma("unroll") for (int co=0;co<30;co++) c[co]=(bp)[co]; \
      _Pragma("unroll") for (int ci=0;ci<30;ci++){ float v=a[ci]; \
        _Pragma("unroll") for (int co=0;co<30;co++) c[co]=fmaf(v,(wp)[ci*30+co],c[co]); } \
      _Pragma("unroll") for (int co=0;co<30;co++) a[co]=fmaxf(c[co],0.f); }

    LAYER30(w1,b1);
    LAYER30(w2,b2);
    LAYER30(w3,b3);
#undef LAYER30

    float* op = out + (size_t)l*30*N_ROWS + n;
    #pragma unroll
    for (int co=0;co<30;co++) op[(size_t)co*N_ROWS] = a[co];
}

// ---------------------------------------------------------------------------
// Kernel 2a: conv weight repack for MFMA, bf16 hi/lo. (unchanged)
// ---------------------------------------------------------------------------
__global__ __launch_bounds__(256) void repack_conv(
    const float* __restrict__ w20, const float* __restrict__ w21,
    const float* __restrict__ w22, const float* __restrict__ w23,
    unsigned short* __restrict__ cwh, unsigned short* __restrict__ cwl)
{
    int i = blockIdx.x*256 + threadIdx.x;
    if (i >= 4*25600) return;
    int layer = i / 25600, r = i - layer*25600;
    int frag = r >> 9, e = r & 511;
    int kt = frag >> 1, ct = frag & 1;
    int lane = e >> 3, j = e & 7;
    int ci = ((lane>>4)<<3) + j;
    int co = ct*16 + (lane & 15);
    const float* w = (layer==0)?w20:(layer==1)?w21:(layer==2)?w22:w23;
    float v = (ci<30 && co<30) ? w[(size_t)(kt*30 + ci)*30 + co] : 0.f;
    unsigned short h = f2bf(v);
    cwh[i] = h; cwl[i] = f2bf(v - bf2f(h));
}

// ---------------------------------------------------------------------------
// Kernel 2b: FUSED 4-layer 5x5 SAME conv + ReLU via split-bf16 MFMA.
// (unchanged from R5 -- measured win, bit-identical output)
// ---------------------------------------------------------------------------
__global__ __launch_bounds__(256, 4) void conv5x5_mfma4(
    float* __restrict__ buf,
    const unsigned short* __restrict__ cwh, const unsigned short* __restrict__ cwl,
    const float* __restrict__ bias0, const float* __restrict__ bias1,
    const float* __restrict__ bias2, const float* __restrict__ bias3)
{
    __shared__ __align__(16) unsigned short imgh[18*17*32];  // 19584 B
    __shared__ __align__(16) unsigned short imgl[18*17*32];

    int bi = blockIdx.x;
    int l = bi >> 6, b = bi & 63;
    float* ip = buf + (size_t)l*30*N_ROWS + (size_t)b*NPIX;
    const int tid = threadIdx.x;
    const int wave = tid >> 6, lane = tid & 63;
    const int m16 = lane & 15, quad = lane >> 4;

    {
        unsigned* zh = (unsigned*)imgh; unsigned* zl = (unsigned*)imgl;
        for (int i=tid; i<18*17*16; i+=256){ zh[i]=0u; zl[i]=0u; }
    }
    __syncthreads();

    for (int i=tid; i<30*NPIX; i+=256){
        int ci = i / NPIX, p = i - ci*NPIX;
        int py = p/13, px = p - py*13;
        float v = ip[(size_t)ci*N_ROWS + p];
        int L = (py+2)*17 + (px+2);
        int o = L*32 + ((((ci>>3) + L)&3)<<3) + (ci&7);
        unsigned short hh = f2bf(v);
        imgh[o] = hh; imgl[o] = f2bf(v - bf2f(hh));
    }

    int pL[3]; bool mv[3];
    #pragma unroll
    for (int mi=0; mi<3; mi++){
        int Mt = wave + mi*4;
        mv[mi] = (Mt < 11);
        int p = Mt*16 + m16;
        int py = p/13, px = p - py*13;
        pL[mi] = py*17 + px;
    }

    #pragma unroll 1
    for (int layer=0; layer<4; layer++){
        const float* bias = (layer==0)?bias0:(layer==1)?bias1:(layer==2)?bias2:bias3;
        const unsigned short* wh = cwh + (size_t)layer*25600;
        const unsigned short* wl = cwl + (size_t)layer*25600;

        __syncthreads();

        float bb[2];
        #pragma unroll
        for (int nt=0; nt<2; nt++){
            int co = nt*16 + m16;
            bb[nt] = (co < 30) ? bias[co] : 0.f;
        }
        facc acc[3][2];
        #pragma unroll
        for (int mi=0; mi<3; mi++)
            #pragma unroll
            for (int nt=0; nt<2; nt++)
                acc[mi][nt] = (facc){bb[nt], bb[nt], bb[nt], bb[nt]};

        #pragma unroll 1
        for (int kt=0; kt<25; kt++){
            int dy = kt/5, dx = kt - dy*5;
            int Ld = dy*17 + dx;
            bfrag ah[3], al[3];
            #pragma unroll
            for (int mi=0; mi<3; mi++){
                if (mv[mi]){
                    int L = pL[mi] + Ld;
                    int o = L*32 + (((quad + L)&3)<<3);
                    ah[mi] = *(const bfrag*)(imgh + o);
                    al[mi] = *(const bfrag*)(imgl + o);
                }
            }
            const unsigned short* whp = wh + (size_t)(kt*2)*512 + lane*8;
            const unsigned short* wlp = wl + (size_t)(kt*2)*512 + lane*8;
            bfrag bh0 = *(const bfrag*)(whp);
            bfrag bh1 = *(const bfrag*)(whp + 512);
            bfrag bl0 = *(const bfrag*)(wlp);
            bfrag bl1 = *(const bfrag*)(wlp + 512);
            #pragma unroll
            for (int mi=0; mi<3; mi++){
                if (mv[mi]){
                    acc[mi][0] = __builtin_amdgcn_mfma_f32_16x16x32_bf16(ah[mi], bh0, acc[mi][0],0,0,0);
                    acc[mi][1] = __builtin_amdgcn_mfma_f32_16x16x32_bf16(ah[mi], bh1, acc[mi][1],0,0,0);
                }
            }
            #pragma unroll
            for (int mi=0; mi<3; mi++){
                if (mv[mi]){
                    acc[mi][0] = __builtin_amdgcn_mfma_f32_16x16x32_bf16(al[mi], bh0, acc[mi][0],0,0,0);
                    acc[mi][1] = __builtin_amdgcn_mfma_f32_16x16x32_bf16(al[mi], bh1, acc[mi][1],0,0,0);
                }
            }
            #pragma unroll
            for (int mi=0; mi<3; mi++){
                if (mv[mi]){
                    acc[mi][0] = __builtin_amdgcn_mfma_f32_16x16x32_bf16(ah[mi], bl0, acc[mi][0],0,0,0);
                    acc[mi][1] = __builtin_amdgcn_mfma_f32_16x16x32_bf16(ah[mi], bl1, acc[mi][1],0,0,0);
                }
            }
        }

        __syncthreads();

        if (layer < 3){
            #pragma unroll
            for (int mi=0; mi<3; mi++){
                if (mv[mi]){
                    int Mt = wave + mi*4;
                    #pragma unroll
                    for (int nt=0; nt<2; nt++){
                        int co = nt*16 + m16;
                        if (co < 30){
                            #pragma unroll
                            for (int i2=0; i2<4; i2++){
                                int p = Mt*16 + quad*4 + i2;
                                if (p < NPIX){
                                    float v = fmaxf(acc[mi][nt][i2], 0.f);
                                    int py = p/13, px = p - py*13;
                                    int L = (py+2)*17 + (px+2);
                                    int o = L*32 + ((((co>>3) + L)&3)<<3) + (co&7);
                                    unsigned short hh = f2bf(v);
                                    imgh[o] = hh; imgl[o] = f2bf(v - bf2f(hh));
                                }
                            }
                        }
                    }
                }
            }
        } else {
            #pragma unroll
            for (int mi=0; mi<3; mi++){
                if (mv[mi]){
                    int Mt = wave + mi*4;
                    #pragma unroll
                    for (int nt=0; nt<2; nt++){
                        int co = nt*16 + m16;
                        if (co < 30){
                            #pragma unroll
                            for (int i2=0; i2<4; i2++){
                                int p = Mt*16 + quad*4 + i2;
                                if (p < NPIX)
                                    ip[(size_t)co*N_ROWS + p] = fmaxf(acc[mi][nt][i2], 0.f);
                            }
                        }
                    }
                }
            }
        }
    }
}

// ---------------------------------------------------------------------------
// Kernel 3: LSTM MFMA weight repack, bf16 hi/lo split. (unchanged)
// ---------------------------------------------------------------------------
__global__ __launch_bounds__(256) void repack_mfma(
    const float* __restrict__ l1w, const float* __restrict__ l1b,
    const float* __restrict__ l2w, const float* __restrict__ l2b,
    unsigned short* __restrict__ bw1h, unsigned short* __restrict__ bw1l,
    unsigned short* __restrict__ bw2h, unsigned short* __restrict__ bw2l,
    float* __restrict__ pbias1, float* __restrict__ pbias2)
{
    const int S1 = 5*32*512;   // 81920
    const int S2 = 7*32*512;   // 114688
    int i = blockIdx.x*256 + threadIdx.x;
    if (i < S1){
        int fr = i >> 9, r = i & 511;
        int kt = fr >> 5, ct = fr & 31;
        int lane = r >> 3, j = r & 7;
        int k = kt*32 + ((lane>>4)<<3) + j;
        int n = lane & 15;
        int cell = ((ct>>2)<<4) + n, g = ct & 3;
        float w = (k<130 && cell<100) ? l1w[(size_t)k*400 + g*100 + cell] : 0.f;
        unsigned short h = f2bf(w);
        bw1h[i] = h; bw1l[i] = f2bf(w - bf2f(h));
    } else if (i < S1 + S2){
        int ii = i - S1;
        int fr = ii >> 9, r = ii & 511;
        int kt = fr >> 5, ct = fr & 31;
        int lane = r >> 3, j = r & 7;
        int k = kt*32 + ((lane>>4)<<3) + j;
        int n = lane & 15;
        int cell = ((ct>>2)<<4) + n, g = ct & 3;
        float w = (k<200 && cell<100) ? l2w[(size_t)k*400 + g*100 + cell] : 0.f;
        unsigned short h = f2bf(w);
        bw2h[ii] = h; bw2l[ii] = f2bf(w - bf2f(h));
    } else if (i < S1+S2+512){
        int col = i - S1 - S2;
        int ct = col >> 4, n = col & 15;
        int cell = ((ct>>2)<<4) + n, g = ct & 3;
        pbias1[col] = (cell<100) ? l1b[g*100+cell] : 0.f;
    } else if (i < S1+S2+1024){
        int col = i - S1 - S2 - 512;
        int ct = col >> 4, n = col & 15;
        int cell = ((ct>>2)<<4) + n, g = ct & 3;
        pbias2[col] = (cell<100) ? l2b[g*100+cell] : 0.f;
    }
}

// ---------------------------------------------------------------------------
// Kernel 4: PERSISTENT 2-layer LSTM + projection, v7 ("M=32 x 8 waves").
// R1-vs-R2 evidence: latency-bound at ~2.6 waves/SIMD (3x traffic change
// moved nothing); grid 676 was the occupancy cap. Per-block weight traffic
// is FIXED (786 KB/step) regardless of M, so: M=32, 512 thr (8 waves),
// grid 338. Critical CUs (82 with 2 blocks) get 4 waves/SIMD (was 2.6) AND
// 1.57 MB/step (was 2.36). Wave w owns cell-tile w (cells 16w..16w+15,
// ct = 4w+g), 2 M-tiles of 16 rows. Per-accumulator MFMA order identical
// to lstm_mfma3 -> bit-identical output (absmax must stay 9.536743e-07).
// launch_bounds(512,4) caps VGPR at 128 (watch FETCH for R4 spill mode).
// ---------------------------------------------------------------------------
#define NKT1 5
#define NKT2 7
#define M_BLK 32
__global__ __launch_bounds__(512, 4) void lstm_mfma6(
    const float* __restrict__ xall,   // [55][30][N]
    const unsigned short* __restrict__ bw1h, const unsigned short* __restrict__ bw1l,
    const unsigned short* __restrict__ bw2h, const unsigned short* __restrict__ bw2l,
    const float* __restrict__ pbias1, const float* __restrict__ pbias2,
    const float* __restrict__ we, const float* __restrict__ be,
    float* __restrict__ out)          // [N][55]
{
    // A matrices bf16 hi/lo, [kt][row(32)][k(32)] ushort (1024/kt-tile)
    __shared__ __align__(16) unsigned short A1h[NKT1*1024];  // 10240 B
    __shared__ __align__(16) unsigned short A1l[NKT1*1024];
    __shared__ __align__(16) unsigned short A2h[NKT2*1024];  // 14336 B
    __shared__ __align__(16) unsigned short A2l[NKT2*1024];
    __shared__ float pbuf[8*M_BLK];                          // 1 KB

    const int tid  = threadIdx.x;
    const int w    = tid >> 6, lane = tid & 63;
    const int m16  = lane & 15, quad = lane >> 4;
    const int n0   = blockIdx.x * M_BLK;
    const int cell = w*16 + m16;          // wave w owns cell-tile w
    const bool cv  = (cell < 100);

    for (int i=tid; i<NKT1*1024; i+=512){ A1h[i]=0; A1l[i]=0; }
    for (int i=tid; i<NKT2*1024; i+=512){ A2h[i]=0; A2l[i]=0; }

    float cs1[2][4] = {{0,0,0,0},{0,0,0,0}};
    float cs2[2][4] = {{0,0,0,0},{0,0,0,0}};
    float b1[4], b2[4];
    #pragma unroll
    for (int g=0; g<4; g++){
        b1[g] = pbias1[(w*4+g)*16 + m16];
        b2[g] = pbias2[(w*4+g)*16 + m16];
    }
    const float weC = cv ? we[cell] : 0.f;
    const float be0 = be[0];

    // weight fragment bases: ct = w*4+g; per kt advance 32*512 = 16384
    const unsigned short* w1h0 = bw1h + ((size_t)(w*4)*64 + lane)*8;
    const unsigned short* w1l0 = bw1l + ((size_t)(w*4)*64 + lane)*8;
    const unsigned short* w2h0 = bw2h + ((size_t)(w*4)*64 + lane)*8;
    const unsigned short* w2l0 = bw2l + ((size_t)(w*4)*64 + lane)*8;

    const int sk = tid >> 3, sq = tid & 7;   // staging role (tid<240)

    __syncthreads();   // zero-init visible

    // stage x(0): column sk (k<30), rows sq*4..sq*4+3 (kt=0 tile)
    if (tid < 240){
        float4 v = *(const float4*)(xall + (size_t)sk*N_ROWS + n0 + sq*4);
        float vv[4] = {v.x, v.y, v.z, v.w};
        #pragma unroll
        for (int j=0;j<4;j++){
            unsigned short hh = f2bf(vv[j]);
            A1h[(sq*4+j)*32 + sk] = hh;
            A1l[(sq*4+j)*32 + sk] = f2bf(vv[j] - bf2f(hh));
        }
    }
    __syncthreads();

    facc acc[2][4];   // [mt][g]

// 3-term split GEMM; per kt: 8 B loads (4 bh + 4 bl), 4 A ds_reads, 24 MFMA.
// Per-accumulator pass order (ah*bh, al*bh, ah*bl per kt) identical to v3.
#define GEMM(WH0, WL0, NKT, AH, AL, BI) \
    { _Pragma("unroll") \
      for (int mt=0; mt<2; mt++) \
        _Pragma("unroll") \
        for (int g=0; g<4; g++){ float bb=(BI)[g]; acc[mt][g]=(facc){bb,bb,bb,bb}; } \
      _Pragma("unroll 1") \
      for (int kt=0; kt<(NKT); kt++){ \
        bfrag ah[2], al[2]; \
        _Pragma("unroll") \
        for (int mt=0; mt<2; mt++){ \
            int off = (kt<<10) + ((mt*16+m16)<<5) + (quad<<3); \
            ah[mt] = *(const bfrag*)((AH) + off); \
            al[mt] = *(const bfrag*)((AL) + off); } \
        const unsigned short* whp = (WH0) + (size_t)kt*16384; \
        const unsigned short* wlp = (WL0) + (size_t)kt*16384; \
        bfrag bh[4], bl[4]; \
        _Pragma("unroll") \
        for (int g=0; g<4; g++){ \
            bh[g] = *(const bfrag*)(whp + (size_t)g*512); \
            bl[g] = *(const bfrag*)(wlp + (size_t)g*512); } \
        _Pragma("unroll") \
        for (int g=0; g<4; g++){ \
            acc[0][g]=__builtin_amdgcn_mfma_f32_16x16x32_bf16(ah[0],bh[g],acc[0][g],0,0,0); \
            acc[1][g]=__builtin_amdgcn_mfma_f32_16x16x32_bf16(ah[1],bh[g],acc[1][g],0,0,0); } \
        _Pragma("unroll") \
        for (int g=0; g<4; g++){ \
            acc[0][g]=__builtin_amdgcn_mfma_f32_16x16x32_bf16(al[0],bh[g],acc[0][g],0,0,0); \
            acc[1][g]=__builtin_amdgcn_mfma_f32_16x16x32_bf16(al[1],bh[g],acc[1][g],0,0,0); } \
        _Pragma("unroll") \
        for (int g=0; g<4; g++){ \
            acc[0][g]=__builtin_amdgcn_mfma_f32_16x16x32_bf16(ah[0],bl[g],acc[0][g],0,0,0); \
            acc[1][g]=__builtin_amdgcn_mfma_f32_16x16x32_bf16(ah[1],bl[g],acc[1][g],0,0,0); } \
      } }

    for (int t=0; t<T_SEQ; t++){
        // prefetch x(t+1); latency hidden under GEMM1
        float4 xn;
        if (t+1 < T_SEQ && tid < 240)
            xn = *(const float4*)(xall + ((size_t)(t+1)*30+sk)*N_ROWS + n0 + sq*4);

        GEMM(w1h0, w1l0, NKT1, A1h, A1l, b1);              // layer 1
        __syncthreads();                                   // B1

        // EPI1: h1 -> A1 (k=30+cell) and A2 (k=cell)
        #pragma unroll
        for (int mt=0; mt<2; mt++){
            #pragma unroll
            for (int i2=0;i2<4;i2++){
                float gi = fast_sig(acc[mt][0][i2]);
                float gj = fast_tanh(acc[mt][1][i2]);
                float gf = fast_sig(acc[mt][2][i2] + 1.0f);
                float go = fast_sig(acc[mt][3][i2]);
                float cn = gf*cs1[mt][i2] + gi*gj;
                cs1[mt][i2] = cn;
                float h = go*fast_tanh(cn);
                if (cv){
                    int row = mt*16 + quad*4 + i2;
                    unsigned short hh = f2bf(h);
                    unsigned short hl = f2bf(h - bf2f(hh));
                    int k1 = 30 + cell;
                    int a1 = ((k1>>5)<<10) + (row<<5) + (k1&31);
                    int a2 = ((cell>>5)<<10) + (row<<5) + (cell&31);
                    A1h[a1]=hh; A1l[a1]=hl;
                    A2h[a2]=hh; A2l[a2]=hl;
                }
            }
        }
        // stage x(t+1) into A1 (GEMM1(t) done reading; next read after B2)
        if (t+1 < T_SEQ && tid < 240){
            float vv[4] = {xn.x, xn.y, xn.z, xn.w};
            #pragma unroll
            for (int j=0;j<4;j++){
                unsigned short hh = f2bf(vv[j]);
                A1h[(sq*4+j)*32 + sk] = hh;
                A1l[(sq*4+j)*32 + sk] = f2bf(vv[j] - bf2f(hh));
            }
        }
        __syncthreads();                                   // B2

        GEMM(w2h0, w2l0, NKT2, A2h, A2l, b2);              // layer 2
        __syncthreads();                                   // B3

        // EPI2: h2 -> A2 (k=100+cell) + in-register projection partial
        {
            float pp[2][4];
            #pragma unroll
            for (int mt=0; mt<2; mt++){
                #pragma unroll
                for (int i2=0;i2<4;i2++){
                    float gi = fast_sig(acc[mt][0][i2]);
                    float gj = fast_tanh(acc[mt][1][i2]);
                    float gf = fast_sig(acc[mt][2][i2] + 1.0f);
                    float go = fast_sig(acc[mt][3][i2]);
                    float cn = gf*cs2[mt][i2] + gi*gj;
                    cs2[mt][i2] = cn;
                    float h = go*fast_tanh(cn);
                    pp[mt][i2] = h*weC;   // we==0 pads cells>=100
                    if (cv){
                        int row = mt*16 + quad*4 + i2;
                        unsigned short hh = f2bf(h);
                        unsigned short hl = f2bf(h - bf2f(hh));
                        int k1 = 100 + cell;
                        int a1 = ((k1>>5)<<10) + (row<<5) + (k1&31);
                        A2h[a1]=hh; A2l[a1]=hl;
                    }
                }
            }
            // reduce over the 16 cells (m16 lanes) of this wave
            #pragma unroll
            for (int mt=0; mt<2; mt++){
                #pragma unroll
                for (int i2=0;i2<4;i2++){
                    float p = pp[mt][i2];
                    p += __shfl_xor(p, 1);
                    p += __shfl_xor(p, 2);
                    p += __shfl_xor(p, 4);
                    p += __shfl_xor(p, 8);
                    pp[mt][i2] = p;
                }
            }
            if (m16 == 0){
                #pragma unroll
                for (int mt=0; mt<2; mt++)
                    #pragma unroll
                    for (int i2=0;i2<4;i2++)
                        pbuf[w*M_BLK + mt*16 + quad*4 + i2] = pp[mt][i2];
            }
        }
        __syncthreads();                                   // B4

        if (tid < M_BLK){
            float s = be0;
            #pragma unroll
            for (int ww=0; ww<8; ww++) s += pbuf[ww*M_BLK + tid];
            out[(size_t)(n0+tid)*T_SEQ + t] = s;
        }
    }
#undef GEMM
}

// ---------------------------------------------------------------------------
extern "C" void kernel_launch(void* const* d_in, const int* in_sizes, int n_in,
                              void* d_out, int out_size, void* d_ws, size_t ws_size,
                              hipStream_t stream)
{
    const float* x    = (const float*)d_in[0];
    const float* w10  = (const float*)d_in[1];  const float* b10 = (const float*)d_in[2];
    const float* w11  = (const float*)d_in[3];  const float* b11 = (const float*)d_in[4];
    const float* w12  = (const float*)d_in[5];  const float* b12 = (const float*)d_in[6];
    const float* w13  = (const float*)d_in[7];  const float* b13 = (const float*)d_in[8];
    const float* w20  = (const float*)d_in[9];  const float* b20 = (const float*)d_in[10];
    const float* w21  = (const float*)d_in[11]; const float* b21 = (const float*)d_in[12];
    const float* w22  = (const float*)d_in[13]; const float* b22 = (const float*)d_in[14];
    const float* w23  = (const float*)d_in[15]; const float* b23 = (const float*)d_in[16];
    const float* l1w  = (const float*)d_in[17]; const float* l1b = (const float*)d_in[18];
    const float* l2w  = (const float*)d_in[19]; const float* l2b = (const float*)d_in[20];
    const float* we   = (const float*)d_in[21]; const float* be  = (const float*)d_in[22];
    float* out = (float*)d_out;

    // workspace: conv slab 71.4 MB + packed bf16 weights ~0.8 MB + biases.
    // Conv packs (409.6 KB) OVERLAY the lstm pack region and are consumed
    // before repack_mfma overwrites it (stream-serialized) -> no extra ws.
    const size_t NF = (size_t)30*N_ROWS;
    float* buf0 = (float*)d_ws;                       // [55][30][N] floats
    unsigned short* bw1h = (unsigned short*)(buf0 + (size_t)T_SEQ*NF);
    unsigned short* bw1l = bw1h + 5*32*512;           // 81920 each
    unsigned short* bw2h = bw1l + 5*32*512;
    unsigned short* bw2l = bw2h + 7*32*512;           // 114688 each
    float* pbias1 = (float*)(bw2l + 7*32*512);
    float* pbias2 = pbias1 + 512;

    unsigned short* cwh = bw1h;                       // 4*25600 ushorts
    unsigned short* cwl = cwh + 4*25600;              // 4*25600 ushorts

    repack_conv<<<(4*25600+255)/256, 256, 0, stream>>>(w20, w21, w22, w23, cwh, cwl);

    dim3 g1((N_ROWS+255)/256, T_SEQ);
    conv1x1_chain<<<g1, 256, 0, stream>>>(x, w10,b10, w11,b11, w12,b12, w13,b13, buf0);

    conv5x5_mfma4<<<T_SEQ*64, 256, 0, stream>>>(buf0, cwh, cwl, b20, b21, b22, b23);

    const int REPACK_N = 5*32*512 + 7*32*512 + 1024;
    repack_mfma<<<(REPACK_N+255)/256, 256, 0, stream>>>(
        l1w, l1b, l2w, l2b, bw1h, bw1l, bw2h, bw2l, pbias1, pbias2);

    lstm_mfma6<<<N_ROWS/M_BLK, 512, 0, stream>>>(buf0, bw1h, bw1l, bw2h, bw2l,
                                                 pbias1, pbias2, we, be, out);
}